// Round 10
// baseline (256.718 us; speedup 1.0000x reference)
//
#include <hip/hip_runtime.h>

// B = in_sizes[0]/840, L=40, A=21. One thread per row, ONE WAVE PER BLOCK
// (LDS wave-private, zero barriers; fence discipline + in-order DS).
// CPOS=4: 336-B per-row segments -> near-ideal FETCH (R8 measured 1.06x).
// R9 change vs R8: __launch_bounds__(64, 1) -> VGPR cap 512 (R8's default
// heuristic capped at 124 and spilled the 168-VGPR float4 double-buffer:
// WRITE_SIZE 417 MB of scratch). ~215 live regs must stay in-register.
#define LPOS 40
#define AA   21
#define ROWF (LPOS*AA)        // 840 floats per row
#define ROW4 (ROWF/4)         // 210 float4 per row
#define CPOS 4
#define CF   (CPOS*AA)        // 84 floats per row-chunk
#define CF4  (CF/4)           // 21 float4 per row-chunk
#define NCH  (LPOS/CPOS)      // 10 bodies
#define NTHR 64               // one wave per block

// Compiler-only fence: orders memory ops across the staging transpose
// (single-thread alias analysis would otherwise hoist next body's ds_reads
// above this body's ds_writes — the R2/R3 bug). HW per-wave DS is in-order.
#define FENCE() asm volatile("" ::: "memory")

__global__ __launch_bounds__(NTHR, 1) void cm_kernel(
    const float* __restrict__ x,
    const float* __restrict__ vg,
    const float* __restrict__ jg,
    float* __restrict__ out)
{
    __shared__ float4 sbuf[NTHR * CF4];   // 21504 B: [64 rows][21 float4]

    const int lane = threadIdx.x;                       // 0..63
    const long long row0 = (long long)blockIdx.x * NTHR;
    const float4* xw4 = (const float4*)x + row0 * ROW4;

    // Per-lane float4 offsets for body 0: flat slot f = lane + 64*i over
    // [64 rows][21 float4]; r = f/21, e = f%21, goff = r*210 + e.
    // Step f += 64  =>  r += 3, e += 1  (wrap: e -= 21, r += 1).
    int goff[CF4];
    {
        int r = lane / AA;
        int e = lane - r * AA;
        int off = r * ROW4 + e;
        #pragma unroll
        for (int i = 0; i < CF4; ++i) {
            goff[i] = off;
            e += 1; off += 3 * ROW4 + 1;
            if (e >= AA) { e -= AA; off += ROW4 - AA; }
        }
    }

    float4 rgA[CF4], rgB[CF4];

    // Prologue: body0 -> rgA, body1 -> rgB (stays in flight), rgA -> LDS
    // (vmcnt waits rgA only), rgA <- body2.
    // Invariant entering k=0: LDS = body0; rgB = body1; rgA = body2.
    #pragma unroll
    for (int i = 0; i < CF4; ++i) rgA[i] = xw4[goff[i]];
    #pragma unroll
    for (int i = 0; i < CF4; ++i) rgB[i] = xw4[goff[i] + CF4];
    FENCE();
    #pragma unroll
    for (int i = 0; i < CF4; ++i) sbuf[lane + i * 64] = rgA[i];
    FENCE();
    #pragma unroll
    for (int i = 0; i < CF4; ++i) rgA[i] = xw4[goff[i] + 2 * CF4];
    FENCE();

    float run = 1.0f, vsum = 0.0f, jsum = 0.0f;

    // Body: compute body k (4 positions) from LDS; overwrite LDS with body
    // k+1 (WAR safe: in-order DS + fences); refill RGW with body k+3.
    #define BODY(k, RGW)                                                   \
      {                                                                    \
        const float* xs = (const float*)&sbuf[lane * CF4];                 \
        _Pragma("unroll")                                                  \
        for (int p = 0; p < CPOS; ++p) {                                   \
          float m = 0.f, jm = 0.f;                                         \
          _Pragma("unroll")                                                \
          for (int a = 0; a < AA; ++a) {                                   \
            const float xv = xs[p * AA + a];                               \
            m  = fmaf(xv, vg[((k) * CPOS + p) * AA + a], m);               \
            jm = fmaf(xv, jg[((k) * CPOS + p) * AA + a], jm);              \
          }                                                                \
          run *= m; vsum += run; jsum += jm;                               \
        }                                                                  \
        FENCE();                                                           \
        if ((k) + 1 < NCH) {                                               \
          _Pragma("unroll")                                                \
          for (int i = 0; i < CF4; ++i) sbuf[lane + i * 64] = RGW[i];      \
          FENCE();                                                         \
          if ((k) + 3 < NCH) {                                             \
            _Pragma("unroll")                                              \
            for (int i = 0; i < CF4; ++i)                                  \
              RGW[i] = xw4[goff[i] + ((k) + 3) * CF4];                     \
            FENCE();                                                       \
          }                                                                \
        }                                                                  \
      }

    for (int k = 0; k < NCH; k += 2) {
        BODY(k,     rgB)   // compute k;   stage k+1 (rgB); rgB <- k+3
        BODY(k + 1, rgA)   // compute k+1; stage k+2 (rgA); rgA <- k+4
    }

    ((float2*)out)[row0 + lane] = make_float2(vsum, jsum);  // coalesced 8B
}

extern "C" void kernel_launch(void* const* d_in, const int* in_sizes, int n_in,
                              void* d_out, int out_size, void* d_ws, size_t ws_size,
                              hipStream_t stream) {
    const float* x  = (const float*)d_in[0];
    const float* vg = (const float*)d_in[1];
    const float* jg = (const float*)d_in[2];
    float* out      = (float*)d_out;

    const int B    = in_sizes[0] / ROWF;   // 131072
    const int grid = B / NTHR;             // 2048

    cm_kernel<<<grid, NTHR, 0, stream>>>(x, vg, jg, out);
}

// Round 11
// 94.807 us; speedup vs baseline: 2.7078x; 2.7078x over previous
//
#include <hip/hip_runtime.h>

// B = in_sizes[0]/840, L=40, A=21. One thread per row, ONE WAVE PER BLOCK.
// CPOS=4 (336-B per-row segments -> measured FETCH 1.06x ideal, R8).
// R10: staging via __builtin_amdgcn_global_load_lds (16B), eliminating the
// register double-buffer the allocator insisted on spilling (R8/R9: VGPR
// capped at 124, 417 MB scratch WRITE_SIZE). LDS double-buffer (43 KB),
// counted s_waitcnt vmcnt(21) per body (T4), no __syncthreads anywhere.
#define LPOS 40
#define AA   21
#define ROWF (LPOS*AA)        // 840 floats per row
#define ROW4 (ROWF/4)         // 210 float4 per row
#define CPOS 4
#define CF   (CPOS*AA)        // 84 floats per row-chunk
#define CF4  (CF/4)           // 21 float4 per row-chunk
#define NCH  (LPOS/CPOS)      // 10 bodies
#define NTHR 64               // one wave per block

__global__ __launch_bounds__(NTHR) void cm_kernel(
    const float* __restrict__ x,
    const float* __restrict__ vg,
    const float* __restrict__ jg,
    float* __restrict__ out)
{
    __shared__ float4 sbuf[2][NTHR * CF4];   // 2 x 21504 B = 43008 B

    const int lane = threadIdx.x;                       // 0..63
    const long long row0 = (long long)blockIdx.x * NTHR;
    const float4* xw4 = (const float4*)x + row0 * ROW4;

    // Per-lane float4 offsets for body 0: flat slot f = lane + 64*i over
    // [64 rows][21 float4]; r = f/21, e = f%21, goff = r*210 + e.
    // Step f += 64  =>  r += 3, e += 1  (wrap: e -= 21, r += 1).
    int goff[CF4];
    {
        int r = lane / AA;
        int e = lane - r * AA;
        int off = r * ROW4 + e;
        #pragma unroll
        for (int i = 0; i < CF4; ++i) {
            goff[i] = off;
            e += 1; off += 3 * ROW4 + 1;
            if (e >= AA) { e -= AA; off += ROW4 - AA; }
        }
    }

    // Issue body k's 21 async global->LDS loads into buffer b.
    // dst is wave-uniform (+lane*16 implicit in HW); src is per-lane.
    #define ISSUE(k, b)                                                    \
      { _Pragma("unroll")                                                  \
        for (int i = 0; i < CF4; ++i)                                      \
          __builtin_amdgcn_global_load_lds(                                \
            (const __attribute__((address_space(1))) void*)                \
                (xw4 + goff[i] + (k) * CF4),                               \
            (__attribute__((address_space(3))) void*)(&sbuf[b][i * 64]),   \
            16, 0, 0); }

    ISSUE(0, 0)
    ISSUE(1, 1)

    float run = 1.0f, vsum = 0.0f, jsum = 0.0f;

    // Body k (compile-time k, buffer b = k&1):
    //  1) wait body k's loads: all but the newest ISSUE batch (21) done.
    //     Robust to stray VMEM in compute sections: strays are older than
    //     the newest batch, so vmcnt(21) drains them too. Last body: 0.
    //  2) compute 4 positions (ds_read_b128 + FMA; v/j uniform -> s_load).
    //  3) lgkmcnt(0): all ds_reads retired before the just-read buffer is
    //     re-targeted by new async writes (WAR close-out).
    //  4) issue body k+2 into this buffer.
    #define BODY(k)                                                        \
      {                                                                    \
        if ((k) == NCH - 1)                                                \
          asm volatile("s_waitcnt vmcnt(0)" ::: "memory");                 \
        else                                                               \
          asm volatile("s_waitcnt vmcnt(21)" ::: "memory");                \
        __builtin_amdgcn_sched_barrier(0);                                 \
        const float* xs = (const float*)&sbuf[(k) & 1][lane * CF4];        \
        _Pragma("unroll")                                                  \
        for (int p = 0; p < CPOS; ++p) {                                   \
          float m = 0.f, jm = 0.f;                                         \
          _Pragma("unroll")                                                \
          for (int a = 0; a < AA; ++a) {                                   \
            const float xv = xs[p * AA + a];                               \
            m  = fmaf(xv, vg[((k) * CPOS + p) * AA + a], m);               \
            jm = fmaf(xv, jg[((k) * CPOS + p) * AA + a], jm);              \
          }                                                                \
          run *= m; vsum += run; jsum += jm;                               \
        }                                                                  \
        if ((k) + 2 < NCH) {                                               \
          asm volatile("s_waitcnt lgkmcnt(0)" ::: "memory");               \
          __builtin_amdgcn_sched_barrier(0);                               \
          ISSUE((k) + 2, (k) & 1)                                          \
        }                                                                  \
      }

    BODY(0) BODY(1) BODY(2) BODY(3) BODY(4)
    BODY(5) BODY(6) BODY(7) BODY(8) BODY(9)

    ((float2*)out)[row0 + lane] = make_float2(vsum, jsum);  // coalesced 8B
}

extern "C" void kernel_launch(void* const* d_in, const int* in_sizes, int n_in,
                              void* d_out, int out_size, void* d_ws, size_t ws_size,
                              hipStream_t stream) {
    const float* x  = (const float*)d_in[0];
    const float* vg = (const float*)d_in[1];
    const float* jg = (const float*)d_in[2];
    float* out      = (float*)d_out;

    const int B    = in_sizes[0] / ROWF;   // 131072
    const int grid = B / NTHR;             // 2048

    cm_kernel<<<grid, NTHR, 0, stream>>>(x, vg, jg, out);
}